// Round 12
// baseline (387.455 us; speedup 1.0000x reference)
//
#include <hip/hip_runtime.h>
#include <hip/hip_fp16.h>
#include <math.h>

typedef _Float16 half8 __attribute__((ext_vector_type(8)));
typedef _Float16 half4v __attribute__((ext_vector_type(4)));
typedef float float4v __attribute__((ext_vector_type(4)));

// ---------------- CSR build (single-atomic counting sort) ----------------

__global__ __launch_bounds__(256) void rank_k(const int* __restrict__ dst, int* cnt,
                                              int* __restrict__ rank, int E) {
    int e = blockIdx.x * 256 + threadIdx.x;
    if (e < E) {
        int d = dst[e];
        rank[e] = atomicAdd(&cnt[d], 1);
    }
}

__global__ __launch_bounds__(256) void scan1_k(const int* __restrict__ cnt, int* bsum, int n) {
    __shared__ int sdata[256];
    int base = blockIdx.x * 1024;
    int t = threadIdx.x;
    int s = 0;
    #pragma unroll
    for (int j = 0; j < 4; j++) {
        int i = base + t * 4 + j;
        if (i < n) s += cnt[i];
    }
    sdata[t] = s;
    __syncthreads();
    for (int off = 128; off > 0; off >>= 1) {
        if (t < off) sdata[t] += sdata[t + off];
        __syncthreads();
    }
    if (t == 0) bsum[blockIdx.x] = sdata[0];
}

__global__ void scan2_k(int* bsum, int nb) {
    if (threadIdx.x == 0 && blockIdx.x == 0) {
        int run = 0;
        for (int b = 0; b < nb; b++) { int v = bsum[b]; bsum[b] = run; run += v; }
    }
}

__global__ __launch_bounds__(256) void scan3_k(const int* __restrict__ cnt, const int* __restrict__ bsum,
                                               int* row_ptr, int n) {
    __shared__ int sdata[256];
    int base = blockIdx.x * 1024;
    int t = threadIdx.x;
    int loc[4];
    int s = 0;
    #pragma unroll
    for (int j = 0; j < 4; j++) {
        int i = base + t * 4 + j;
        loc[j] = (i < n) ? cnt[i] : 0;
        s += loc[j];
    }
    sdata[t] = s;
    __syncthreads();
    for (int off = 1; off < 256; off <<= 1) {
        int v = (t >= off) ? sdata[t - off] : 0;
        __syncthreads();
        sdata[t] += v;
        __syncthreads();
    }
    int excl = sdata[t] - s;
    int run = bsum[blockIdx.x] + excl;
    #pragma unroll
    for (int j = 0; j < 4; j++) {
        int i = base + t * 4 + j;
        if (i < n) row_ptr[i] = run;
        run += loc[j];
    }
}

__global__ __launch_bounds__(256) void fill_k(const int* __restrict__ src, const int* __restrict__ dst,
                                              const float* __restrict__ ew,
                                              const int* __restrict__ row_ptr,
                                              const int* __restrict__ rank,
                                              int2* __restrict__ meta, int E) {
    int e = blockIdx.x * 256 + threadIdx.x;
    if (e < E) {
        int d = dst[e];
        int pos = row_ptr[d] + rank[e];
        meta[pos] = make_int2(src[e], __float_as_int(ew[e]));
    }
}

__global__ __launch_bounds__(256) void deg_k(const int2* __restrict__ meta,
                                             const int* __restrict__ row_ptr,
                                             const int* __restrict__ cnt,
                                             float* __restrict__ dinv, int n) {
    int d = blockIdx.x * 256 + threadIdx.x;
    if (d < n) {
        int start = row_ptr[d];
        int c = cnt[d];
        float s = 1.0f;
        for (int j = 0; j < c; j++) s += __int_as_float(meta[start + j].y);
        dinv[d] = rsqrtf(s);
    }
}

__global__ __launch_bounds__(256) void scale_k(int2* __restrict__ meta,
                                               const float* __restrict__ dinv, int E) {
    int e = blockIdx.x * 256 + threadIdx.x;
    if (e < E) {
        int2 m = meta[e];
        float wn = __int_as_float(m.y) * dinv[m.x];
        ((int*)meta)[2 * e + 1] = __float_as_int(wn);
    }
}

// ---------------- converts ----------------

// W[K][128] fp32 -> WT[128][K] fp16 (x3), plus FW[128][10] -> fwh[16][128] fp16
__global__ __launch_bounds__(256) void cvtw_k(const float* __restrict__ W1, const float* __restrict__ W2,
                                              const float* __restrict__ W3, const float* __restrict__ FW,
                                              _Float16* __restrict__ T1, _Float16* __restrict__ T2,
                                              _Float16* __restrict__ T3, _Float16* __restrict__ fwh,
                                              int F, int Hd) {
    int i = blockIdx.x * 256 + threadIdx.x;
    int n1 = F * Hd, n2 = Hd * Hd;
    if (i < n1) {
        int k = i >> 7, n = i & 127;
        T1[n * F + k] = (_Float16)W1[i];
    } else if (i < n1 + n2) {
        int j = i - n1; int k = j >> 7, n = j & 127;
        T2[n * Hd + k] = (_Float16)W2[j];
    } else if (i < n1 + 2 * n2) {
        int j = i - n1 - n2; int k = j >> 7, n = j & 127;
        T3[n * Hd + k] = (_Float16)W3[j];
    } else if (i < n1 + 2 * n2 + 16 * 128) {
        int j = i - n1 - 2 * n2;           // j = c*128 + f
        int c = j >> 7, f = j & 127;
        fwh[j] = (c < 10) ? (_Float16)FW[f * 10 + c] : (_Float16)0.0f;
    }
}

// ---------------- MFMA fp16 GEMM: T[M,128] = A[M,K] @ BT[128,K]^T ----------
// 256 threads = 4 waves. BM=64 (4 stripes of 16), BK=64.
// Wave w owns N-tiles {2w, 2w+1} across all 4 M-stripes.
// mfma_f32_16x16x32_f16; A/B use the same per-lane k mapping so any
// k-permutation cancels. C/D: col=lane&15, row=(lane>>4)*4+reg (HW-verified).

__global__ __launch_bounds__(256) void gemmh_k(const _Float16* __restrict__ A,
                                               const _Float16* __restrict__ BT,
                                               _Float16* __restrict__ T, int M, int K) {
    __shared__ __align__(16) _Float16 As[64][72];    // +8 pad: 144B row stride
    __shared__ __align__(16) _Float16 Bs[128][72];
    int tid = threadIdx.x;
    int w = tid >> 6, l = tid & 63;
    int lr = l & 15, lk = l >> 4;
    int row0 = blockIdx.x * 64;
    float4v acc[4][2];
    #pragma unroll
    for (int s = 0; s < 4; s++)
        #pragma unroll
        for (int n = 0; n < 2; n++)
            acc[s][n] = (float4v){0.f, 0.f, 0.f, 0.f};

    for (int k0 = 0; k0 < K; k0 += 64) {
        #pragma unroll
        for (int j = 0; j < 2; j++) {
            int idx = tid + j * 256;          // 0..511
            int r = idx >> 3;                 // 0..63
            int c8 = (idx & 7) * 8;           // 0..56
            int gm = row0 + r;
            half8 v = {0, 0, 0, 0, 0, 0, 0, 0};
            if (gm < M) v = *(const half8*)(A + (size_t)gm * K + k0 + c8);
            *(half8*)(&As[r][c8]) = v;
        }
        #pragma unroll
        for (int j = 0; j < 4; j++) {
            int idx = tid + j * 256;          // 0..1023
            int r = idx >> 3;                 // 0..127
            int c8 = (idx & 7) * 8;
            *(half8*)(&Bs[r][c8]) = *(const half8*)(BT + (size_t)r * K + k0 + c8);
        }
        __syncthreads();
        half8 af[4][2], bf[2][2];
        #pragma unroll
        for (int s = 0; s < 4; s++)
            #pragma unroll
            for (int ks = 0; ks < 2; ks++)
                af[s][ks] = *(const half8*)(&As[s * 16 + lr][ks * 32 + lk * 8]);
        #pragma unroll
        for (int n = 0; n < 2; n++)
            #pragma unroll
            for (int ks = 0; ks < 2; ks++)
                bf[n][ks] = *(const half8*)(&Bs[(2 * w + n) * 16 + lr][ks * 32 + lk * 8]);
        #pragma unroll
        for (int s = 0; s < 4; s++) {
            #pragma unroll
            for (int n = 0; n < 2; n++) {
                acc[s][n] = __builtin_amdgcn_mfma_f32_16x16x32_f16(af[s][0], bf[n][0], acc[s][n], 0, 0, 0);
                acc[s][n] = __builtin_amdgcn_mfma_f32_16x16x32_f16(af[s][1], bf[n][1], acc[s][n], 0, 0, 0);
            }
        }
        __syncthreads();
    }
    #pragma unroll
    for (int s = 0; s < 4; s++) {
        int gr0 = row0 + s * 16 + lk * 4;
        #pragma unroll
        for (int n = 0; n < 2; n++) {
            int col = (2 * w + n) * 16 + lr;
            #pragma unroll
            for (int j = 0; j < 4; j++) {
                int gm = gr0 + j;
                if (gm < M) T[(size_t)gm * 128 + col] = (_Float16)acc[s][n][j];
            }
        }
    }
}

// ---- same GEMM but A is fp32, converted during staging (layer 1 only) ----

__global__ __launch_bounds__(256) void gemmx_k(const float* __restrict__ A,
                                               const _Float16* __restrict__ BT,
                                               _Float16* __restrict__ T, int M, int K) {
    __shared__ __align__(16) _Float16 As[64][72];
    __shared__ __align__(16) _Float16 Bs[128][72];
    int tid = threadIdx.x;
    int w = tid >> 6, l = tid & 63;
    int lr = l & 15, lk = l >> 4;
    int row0 = blockIdx.x * 64;
    float4v acc[4][2];
    #pragma unroll
    for (int s = 0; s < 4; s++)
        #pragma unroll
        for (int n = 0; n < 2; n++)
            acc[s][n] = (float4v){0.f, 0.f, 0.f, 0.f};

    for (int k0 = 0; k0 < K; k0 += 64) {
        // stage A tile 64x64: 1024 float4 chunks, convert fp32->fp16
        #pragma unroll
        for (int j = 0; j < 4; j++) {
            int idx = tid + j * 256;          // 0..1023
            int r = idx >> 4;                 // 0..63 (16 chunks per row)
            int c4 = (idx & 15) * 4;
            int gm = row0 + r;
            float4 v = make_float4(0.f, 0.f, 0.f, 0.f);
            if (gm < M) v = *(const float4*)(A + (size_t)gm * K + k0 + c4);
            half4v h = {(_Float16)v.x, (_Float16)v.y, (_Float16)v.z, (_Float16)v.w};
            *(half4v*)(&As[r][c4]) = h;
        }
        #pragma unroll
        for (int j = 0; j < 4; j++) {
            int idx = tid + j * 256;
            int r = idx >> 3;
            int c8 = (idx & 7) * 8;
            *(half8*)(&Bs[r][c8]) = *(const half8*)(BT + (size_t)r * K + k0 + c8);
        }
        __syncthreads();
        half8 af[4][2], bf[2][2];
        #pragma unroll
        for (int s = 0; s < 4; s++)
            #pragma unroll
            for (int ks = 0; ks < 2; ks++)
                af[s][ks] = *(const half8*)(&As[s * 16 + lr][ks * 32 + lk * 8]);
        #pragma unroll
        for (int n = 0; n < 2; n++)
            #pragma unroll
            for (int ks = 0; ks < 2; ks++)
                bf[n][ks] = *(const half8*)(&Bs[(2 * w + n) * 16 + lr][ks * 32 + lk * 8]);
        #pragma unroll
        for (int s = 0; s < 4; s++) {
            #pragma unroll
            for (int n = 0; n < 2; n++) {
                acc[s][n] = __builtin_amdgcn_mfma_f32_16x16x32_f16(af[s][0], bf[n][0], acc[s][n], 0, 0, 0);
                acc[s][n] = __builtin_amdgcn_mfma_f32_16x16x32_f16(af[s][1], bf[n][1], acc[s][n], 0, 0, 0);
            }
        }
        __syncthreads();
    }
    #pragma unroll
    for (int s = 0; s < 4; s++) {
        int gr0 = row0 + s * 16 + lk * 4;
        #pragma unroll
        for (int n = 0; n < 2; n++) {
            int col = (2 * w + n) * 16 + lr;
            #pragma unroll
            for (int j = 0; j < 4; j++) {
                int gm = gr0 + j;
                if (gm < M) T[(size_t)gm * 128 + col] = (_Float16)acc[s][n][j];
            }
        }
    }
}

// ---------------- aggregation + bias + relu (wave per node, fp16 in/out) ----
// Uniform masked batches of 8 with next-batch meta prefetch: 8 independent
// 256B gathers in flight per wave. Tail slots clamp to the last edge with
// zero weight (duplicate-row gathers are cache-hot, ~free).

__global__ __launch_bounds__(256) void agg_k(const __half2* __restrict__ Th, __half2* __restrict__ Hh,
                                             const int2* __restrict__ meta,
                                             const int* __restrict__ row_ptr, const int* __restrict__ cnt,
                                             const float* __restrict__ dinv, const float* __restrict__ bias,
                                             int n) {
    int wave = threadIdx.x >> 6, lane = threadIdx.x & 63;
    int d = blockIdx.x * 4 + wave;
    if (d >= n) return;
    float nd = dinv[d];
    float2 ts = __half22float2(Th[(size_t)d * 64 + lane]);
    float ax = nd * ts.x;
    float ay = nd * ts.y;
    int start = row_ptr[d];
    int c = cnt[d];
    if (c > 0) {
        int last = start + c - 1;
        int2 m[8];
        #pragma unroll
        for (int t = 0; t < 8; t++) {
            int idx = start + t;
            m[t] = meta[idx <= last ? idx : last];
            if (t >= c) m[t].y = 0;       // 0 bits == 0.0f weight
        }
        for (int jb = 0; jb < c; jb += 8) {
            int2 nm[8];
            int nb = jb + 8;
            #pragma unroll
            for (int t = 0; t < 8; t++) {
                int idx = start + nb + t;
                nm[t] = meta[idx <= last ? idx : last];
                if (nb + t >= c) nm[t].y = 0;
            }
            #pragma unroll
            for (int t = 0; t < 8; t++) {
                float2 tv = __half22float2(Th[(size_t)m[t].x * 64 + lane]);
                float wt = __int_as_float(m[t].y);
                ax = fmaf(wt, tv.x, ax);
                ay = fmaf(wt, tv.y, ay);
            }
            #pragma unroll
            for (int t = 0; t < 8; t++) m[t] = nm[t];
        }
    }
    float2 bb = *(const float2*)(bias + 2 * lane);
    float vx = fmaf(nd, ax, bb.x);
    float vy = fmaf(nd, ay, bb.y);
    vx = vx > 0.f ? vx : 0.f;
    vy = vy > 0.f ? vy : 0.f;
    Hh[(size_t)d * 64 + lane] = __floats2half2_rn(vx, vy);
}

// ---------------- final FC(128->10) + softmax: MFMA 64x16 per block --------

__global__ __launch_bounds__(256) void fc_k(const _Float16* __restrict__ Hh,
                                            const _Float16* __restrict__ fwh,
                                            const float* __restrict__ FB,
                                            float* __restrict__ out, int n) {
    __shared__ __align__(16) _Float16 Hs[64][136];   // 64 rows x 128, +8 pad
    __shared__ __align__(16) _Float16 Bs[16][136];   // fwh staged
    __shared__ float fbs[16];
    int tid = threadIdx.x;
    int r0 = blockIdx.x * 64;
    #pragma unroll
    for (int j = 0; j < 4; j++) {
        int idx = tid + j * 256;
        int r = idx >> 4;                 // 16 chunks per row
        int c8 = (idx & 15) * 8;
        int gm = r0 + r;
        half8 v = {0, 0, 0, 0, 0, 0, 0, 0};
        if (gm < n) v = *(const half8*)(Hh + (size_t)gm * 128 + c8);
        *(half8*)(&Hs[r][c8]) = v;
    }
    {
        int r = tid >> 4;
        int c8 = (tid & 15) * 8;
        *(half8*)(&Bs[r][c8]) = *(const half8*)(fwh + r * 128 + c8);
    }
    if (tid < 16) fbs[tid] = (tid < 10) ? FB[tid] : 0.f;
    __syncthreads();

    int w = tid >> 6, l = tid & 63;
    int lr = l & 15, lk = l >> 4;
    half8 af[4], bf[4];
    #pragma unroll
    for (int ks = 0; ks < 4; ks++) {
        af[ks] = *(const half8*)(&Hs[w * 16 + lr][ks * 32 + lk * 8]);
        bf[ks] = *(const half8*)(&Bs[lr][ks * 32 + lk * 8]);
    }
    float4v acc = (float4v){0.f, 0.f, 0.f, 0.f};
    #pragma unroll
    for (int ks = 0; ks < 4; ks++)
        acc = __builtin_amdgcn_mfma_f32_16x16x32_f16(af[ks], bf[ks], acc, 0, 0, 0);

    float fbv = fbs[lr];
    float v[4], mx[4], e[4], sm[4];
    #pragma unroll
    for (int j = 0; j < 4; j++) v[j] = (lr < 10) ? acc[j] + fbv : -1e30f;
    #pragma unroll
    for (int j = 0; j < 4; j++) mx[j] = v[j];
    #pragma unroll
    for (int off = 1; off < 16; off <<= 1) {
        #pragma unroll
        for (int j = 0; j < 4; j++) mx[j] = fmaxf(mx[j], __shfl_xor(mx[j], off));
    }
    #pragma unroll
    for (int j = 0; j < 4; j++) e[j] = __expf(v[j] - mx[j]);
    #pragma unroll
    for (int j = 0; j < 4; j++) sm[j] = e[j];
    #pragma unroll
    for (int off = 1; off < 16; off <<= 1) {
        #pragma unroll
        for (int j = 0; j < 4; j++) sm[j] += __shfl_xor(sm[j], off);
    }
    if (lr < 10) {
        #pragma unroll
        for (int j = 0; j < 4; j++) {
            int gm = r0 + w * 16 + lk * 4 + j;
            if (gm < n) out[(size_t)gm * 10 + lr] = e[j] / sm[j];
        }
    }
}

// ---------------- host ----------------

extern "C" void kernel_launch(void* const* d_in, const int* in_sizes, int n_in,
                              void* d_out, int out_size, void* d_ws, size_t ws_size,
                              hipStream_t stream) {
    const float* x  = (const float*)d_in[0];
    const int*   ei = (const int*)d_in[1];
    const float* ew = (const float*)d_in[2];
    const float* W1 = (const float*)d_in[3];
    const float* b1 = (const float*)d_in[4];
    const float* W2 = (const float*)d_in[5];
    const float* b2 = (const float*)d_in[6];
    const float* W3 = (const float*)d_in[7];
    const float* b3 = (const float*)d_in[8];
    const float* FW = (const float*)d_in[9];
    const float* FB = (const float*)d_in[10];
    float* out = (float*)d_out;

    int Hd = in_sizes[4];            // 128
    int F  = in_sizes[3] / Hd;       // 256
    int N  = in_sizes[0] / F;        // 50000
    int E  = in_sizes[1] / 2;        // 800000

    const int* src = ei;
    const int* dst = ei + E;

    char* ws = (char*)d_ws;
    size_t off = 0;
    auto alloc = [&](size_t bytes) -> void* {
        void* p = ws + off;
        off = (off + bytes + 255) & ~(size_t)255;
        return p;
    };
    float*    dinv    = (float*)alloc((size_t)N * 4);
    int*      cnt     = (int*)alloc((size_t)N * 4);
    int*      row_ptr = (int*)alloc((size_t)N * 4);
    int*      rank    = (int*)alloc((size_t)E * 4);
    int*      bsum    = (int*)alloc(4096);
    int2*     meta    = (int2*)alloc((size_t)E * 8);
    _Float16* T       = (_Float16*)alloc((size_t)N * Hd * 2);
    _Float16* Hh      = (_Float16*)alloc((size_t)N * Hd * 2);
    _Float16* WT1     = (_Float16*)alloc(((size_t)(F + 2 * Hd) * Hd + 16 * 128) * 2);
    _Float16* WT2     = WT1 + (size_t)F * Hd;
    _Float16* WT3     = WT2 + (size_t)Hd * Hd;
    _Float16* fwh     = WT3 + (size_t)Hd * Hd;

    int nb = (N + 1023) / 1024;

    // weight converts
    int nw = (F + 2 * Hd) * Hd + 16 * 128;
    cvtw_k<<<(nw + 255) / 256, 256, 0, stream>>>(W1, W2, W3, FW, WT1, WT2, WT3, fwh, F, Hd);

    // CSR build
    hipMemsetAsync(cnt, 0, (size_t)N * 4, stream);
    rank_k<<<(E + 255) / 256, 256, 0, stream>>>(dst, cnt, rank, E);
    scan1_k<<<nb, 256, 0, stream>>>(cnt, bsum, N);
    scan2_k<<<1, 64, 0, stream>>>(bsum, nb);
    scan3_k<<<nb, 256, 0, stream>>>(cnt, bsum, row_ptr, N);
    fill_k<<<(E + 255) / 256, 256, 0, stream>>>(src, dst, ew, row_ptr, rank, meta, E);
    deg_k<<<(N + 255) / 256, 256, 0, stream>>>(meta, row_ptr, cnt, dinv, N);
    scale_k<<<(E + 255) / 256, 256, 0, stream>>>(meta, dinv, E);

    int gb = (N + 63) / 64;
    int ab = (N + 3) / 4;
    // layer 1 (fused fp32->fp16 convert in A staging)
    gemmx_k<<<gb, 256, 0, stream>>>(x, WT1, T, N, F);
    agg_k<<<ab, 256, 0, stream>>>((const __half2*)T, (__half2*)Hh, meta, row_ptr, cnt, dinv, b1, N);
    // layer 2
    gemmh_k<<<gb, 256, 0, stream>>>(Hh, WT2, T, N, Hd);
    agg_k<<<ab, 256, 0, stream>>>((const __half2*)T, (__half2*)Hh, meta, row_ptr, cnt, dinv, b2, N);
    // layer 3
    gemmh_k<<<gb, 256, 0, stream>>>(Hh, WT3, T, N, Hd);
    agg_k<<<ab, 256, 0, stream>>>((const __half2*)T, (__half2*)Hh, meta, row_ptr, cnt, dinv, b3, N);
    // FC + softmax (MFMA)
    fc_k<<<gb, 256, 0, stream>>>(Hh, fwh, FB, out, N);
}

// Round 14
// 343.606 us; speedup vs baseline: 1.1276x; 1.1276x over previous
//
#include <hip/hip_runtime.h>
#include <hip/hip_fp16.h>
#include <math.h>

typedef _Float16 half8 __attribute__((ext_vector_type(8)));
typedef _Float16 half4v __attribute__((ext_vector_type(4)));
typedef float float4v __attribute__((ext_vector_type(4)));

// ---------------- CSR build (single-atomic counting sort) ----------------

__global__ __launch_bounds__(256) void rank_k(const int* __restrict__ dst, int* cnt,
                                              int* __restrict__ rank, int E) {
    int e = blockIdx.x * 256 + threadIdx.x;
    if (e < E) {
        int d = dst[e];
        rank[e] = atomicAdd(&cnt[d], 1);
    }
}

__global__ __launch_bounds__(256) void scan1_k(const int* __restrict__ cnt, int* bsum, int n) {
    __shared__ int sdata[256];
    int base = blockIdx.x * 1024;
    int t = threadIdx.x;
    int s = 0;
    #pragma unroll
    for (int j = 0; j < 4; j++) {
        int i = base + t * 4 + j;
        if (i < n) s += cnt[i];
    }
    sdata[t] = s;
    __syncthreads();
    for (int off = 128; off > 0; off >>= 1) {
        if (t < off) sdata[t] += sdata[t + off];
        __syncthreads();
    }
    if (t == 0) bsum[blockIdx.x] = sdata[0];
}

__global__ void scan2_k(int* bsum, int nb) {
    if (threadIdx.x == 0 && blockIdx.x == 0) {
        int run = 0;
        for (int b = 0; b < nb; b++) { int v = bsum[b]; bsum[b] = run; run += v; }
    }
}

__global__ __launch_bounds__(256) void scan3_k(const int* __restrict__ cnt, const int* __restrict__ bsum,
                                               int* row_ptr, int n) {
    __shared__ int sdata[256];
    int base = blockIdx.x * 1024;
    int t = threadIdx.x;
    int loc[4];
    int s = 0;
    #pragma unroll
    for (int j = 0; j < 4; j++) {
        int i = base + t * 4 + j;
        loc[j] = (i < n) ? cnt[i] : 0;
        s += loc[j];
    }
    sdata[t] = s;
    __syncthreads();
    for (int off = 1; off < 256; off <<= 1) {
        int v = (t >= off) ? sdata[t - off] : 0;
        __syncthreads();
        sdata[t] += v;
        __syncthreads();
    }
    int excl = sdata[t] - s;
    int run = bsum[blockIdx.x] + excl;
    #pragma unroll
    for (int j = 0; j < 4; j++) {
        int i = base + t * 4 + j;
        if (i < n) row_ptr[i] = run;
        run += loc[j];
    }
}

__global__ __launch_bounds__(256) void fill_k(const int* __restrict__ src, const int* __restrict__ dst,
                                              const float* __restrict__ ew,
                                              const int* __restrict__ row_ptr,
                                              const int* __restrict__ rank,
                                              int2* __restrict__ meta, int E) {
    int e = blockIdx.x * 256 + threadIdx.x;
    if (e < E) {
        int d = dst[e];
        int pos = row_ptr[d] + rank[e];
        meta[pos] = make_int2(src[e], __float_as_int(ew[e]));
    }
}

__global__ __launch_bounds__(256) void deg_k(const int2* __restrict__ meta,
                                             const int* __restrict__ row_ptr,
                                             const int* __restrict__ cnt,
                                             float* __restrict__ dinv, int n) {
    int d = blockIdx.x * 256 + threadIdx.x;
    if (d < n) {
        int start = row_ptr[d];
        int c = cnt[d];
        float s = 1.0f;
        for (int j = 0; j < c; j++) s += __int_as_float(meta[start + j].y);
        dinv[d] = rsqrtf(s);
    }
}

__global__ __launch_bounds__(256) void scale_k(int2* __restrict__ meta,
                                               const float* __restrict__ dinv, int E) {
    int e = blockIdx.x * 256 + threadIdx.x;
    if (e < E) {
        int2 m = meta[e];
        float wn = __int_as_float(m.y) * dinv[m.x];
        ((int*)meta)[2 * e + 1] = __float_as_int(wn);
    }
}

// ---------------- converts ----------------

// W[K][128] fp32 -> WT[128][K] fp16 (x3), plus FW[128][10] -> fwh[16][128] fp16
__global__ __launch_bounds__(256) void cvtw_k(const float* __restrict__ W1, const float* __restrict__ W2,
                                              const float* __restrict__ W3, const float* __restrict__ FW,
                                              _Float16* __restrict__ T1, _Float16* __restrict__ T2,
                                              _Float16* __restrict__ T3, _Float16* __restrict__ fwh,
                                              int F, int Hd) {
    int i = blockIdx.x * 256 + threadIdx.x;
    int n1 = F * Hd, n2 = Hd * Hd;
    if (i < n1) {
        int k = i >> 7, n = i & 127;
        T1[n * F + k] = (_Float16)W1[i];
    } else if (i < n1 + n2) {
        int j = i - n1; int k = j >> 7, n = j & 127;
        T2[n * Hd + k] = (_Float16)W2[j];
    } else if (i < n1 + 2 * n2) {
        int j = i - n1 - n2; int k = j >> 7, n = j & 127;
        T3[n * Hd + k] = (_Float16)W3[j];
    } else if (i < n1 + 2 * n2 + 16 * 128) {
        int j = i - n1 - 2 * n2;           // j = c*128 + f
        int c = j >> 7, f = j & 127;
        fwh[j] = (c < 10) ? (_Float16)FW[f * 10 + c] : (_Float16)0.0f;
    }
}

// ---------------- MFMA fp16 GEMM: T[M,128] = A[M,K] @ BT[128,K]^T ----------
// 256 threads = 4 waves. BM=64 (4 stripes of 16), BK=64.
// Wave w owns N-tiles {2w, 2w+1} across all 4 M-stripes.
// mfma_f32_16x16x32_f16; A/B use the same per-lane k mapping so any
// k-permutation cancels. C/D: col=lane&15, row=(lane>>4)*4+reg (HW-verified).

__global__ __launch_bounds__(256) void gemmh_k(const _Float16* __restrict__ A,
                                               const _Float16* __restrict__ BT,
                                               _Float16* __restrict__ T, int M, int K) {
    __shared__ __align__(16) _Float16 As[64][72];    // +8 pad: 144B row stride
    __shared__ __align__(16) _Float16 Bs[128][72];
    int tid = threadIdx.x;
    int w = tid >> 6, l = tid & 63;
    int lr = l & 15, lk = l >> 4;
    int row0 = blockIdx.x * 64;
    float4v acc[4][2];
    #pragma unroll
    for (int s = 0; s < 4; s++)
        #pragma unroll
        for (int n = 0; n < 2; n++)
            acc[s][n] = (float4v){0.f, 0.f, 0.f, 0.f};

    for (int k0 = 0; k0 < K; k0 += 64) {
        #pragma unroll
        for (int j = 0; j < 2; j++) {
            int idx = tid + j * 256;          // 0..511
            int r = idx >> 3;                 // 0..63
            int c8 = (idx & 7) * 8;           // 0..56
            int gm = row0 + r;
            half8 v = {0, 0, 0, 0, 0, 0, 0, 0};
            if (gm < M) v = *(const half8*)(A + (size_t)gm * K + k0 + c8);
            *(half8*)(&As[r][c8]) = v;
        }
        #pragma unroll
        for (int j = 0; j < 4; j++) {
            int idx = tid + j * 256;          // 0..1023
            int r = idx >> 3;                 // 0..127
            int c8 = (idx & 7) * 8;
            *(half8*)(&Bs[r][c8]) = *(const half8*)(BT + (size_t)r * K + k0 + c8);
        }
        __syncthreads();
        half8 af[4][2], bf[2][2];
        #pragma unroll
        for (int s = 0; s < 4; s++)
            #pragma unroll
            for (int ks = 0; ks < 2; ks++)
                af[s][ks] = *(const half8*)(&As[s * 16 + lr][ks * 32 + lk * 8]);
        #pragma unroll
        for (int n = 0; n < 2; n++)
            #pragma unroll
            for (int ks = 0; ks < 2; ks++)
                bf[n][ks] = *(const half8*)(&Bs[(2 * w + n) * 16 + lr][ks * 32 + lk * 8]);
        #pragma unroll
        for (int s = 0; s < 4; s++) {
            #pragma unroll
            for (int n = 0; n < 2; n++) {
                acc[s][n] = __builtin_amdgcn_mfma_f32_16x16x32_f16(af[s][0], bf[n][0], acc[s][n], 0, 0, 0);
                acc[s][n] = __builtin_amdgcn_mfma_f32_16x16x32_f16(af[s][1], bf[n][1], acc[s][n], 0, 0, 0);
            }
        }
        __syncthreads();
    }
    #pragma unroll
    for (int s = 0; s < 4; s++) {
        int gr0 = row0 + s * 16 + lk * 4;
        #pragma unroll
        for (int n = 0; n < 2; n++) {
            int col = (2 * w + n) * 16 + lr;
            #pragma unroll
            for (int j = 0; j < 4; j++) {
                int gm = gr0 + j;
                if (gm < M) T[(size_t)gm * 128 + col] = (_Float16)acc[s][n][j];
            }
        }
    }
}

// ---- same GEMM but A is fp32, converted during staging (layer 1 only) ----

__global__ __launch_bounds__(256) void gemmx_k(const float* __restrict__ A,
                                               const _Float16* __restrict__ BT,
                                               _Float16* __restrict__ T, int M, int K) {
    __shared__ __align__(16) _Float16 As[64][72];
    __shared__ __align__(16) _Float16 Bs[128][72];
    int tid = threadIdx.x;
    int w = tid >> 6, l = tid & 63;
    int lr = l & 15, lk = l >> 4;
    int row0 = blockIdx.x * 64;
    float4v acc[4][2];
    #pragma unroll
    for (int s = 0; s < 4; s++)
        #pragma unroll
        for (int n = 0; n < 2; n++)
            acc[s][n] = (float4v){0.f, 0.f, 0.f, 0.f};

    for (int k0 = 0; k0 < K; k0 += 64) {
        // stage A tile 64x64: 1024 float4 chunks, convert fp32->fp16
        #pragma unroll
        for (int j = 0; j < 4; j++) {
            int idx = tid + j * 256;          // 0..1023
            int r = idx >> 4;                 // 0..63 (16 chunks per row)
            int c4 = (idx & 15) * 4;
            int gm = row0 + r;
            float4 v = make_float4(0.f, 0.f, 0.f, 0.f);
            if (gm < M) v = *(const float4*)(A + (size_t)gm * K + k0 + c4);
            half4v h = {(_Float16)v.x, (_Float16)v.y, (_Float16)v.z, (_Float16)v.w};
            *(half4v*)(&As[r][c4]) = h;
        }
        #pragma unroll
        for (int j = 0; j < 4; j++) {
            int idx = tid + j * 256;
            int r = idx >> 3;
            int c8 = (idx & 7) * 8;
            *(half8*)(&Bs[r][c8]) = *(const half8*)(BT + (size_t)r * K + k0 + c8);
        }
        __syncthreads();
        half8 af[4][2], bf[2][2];
        #pragma unroll
        for (int s = 0; s < 4; s++)
            #pragma unroll
            for (int ks = 0; ks < 2; ks++)
                af[s][ks] = *(const half8*)(&As[s * 16 + lr][ks * 32 + lk * 8]);
        #pragma unroll
        for (int n = 0; n < 2; n++)
            #pragma unroll
            for (int ks = 0; ks < 2; ks++)
                bf[n][ks] = *(const half8*)(&Bs[(2 * w + n) * 16 + lr][ks * 32 + lk * 8]);
        #pragma unroll
        for (int s = 0; s < 4; s++) {
            #pragma unroll
            for (int n = 0; n < 2; n++) {
                acc[s][n] = __builtin_amdgcn_mfma_f32_16x16x32_f16(af[s][0], bf[n][0], acc[s][n], 0, 0, 0);
                acc[s][n] = __builtin_amdgcn_mfma_f32_16x16x32_f16(af[s][1], bf[n][1], acc[s][n], 0, 0, 0);
            }
        }
        __syncthreads();
    }
    #pragma unroll
    for (int s = 0; s < 4; s++) {
        int gr0 = row0 + s * 16 + lk * 4;
        #pragma unroll
        for (int n = 0; n < 2; n++) {
            int col = (2 * w + n) * 16 + lr;
            #pragma unroll
            for (int j = 0; j < 4; j++) {
                int gm = gr0 + j;
                if (gm < M) T[(size_t)gm * 128 + col] = (_Float16)acc[s][n][j];
            }
        }
    }
}

// ---------------- aggregation + bias + relu (wave per node, fp16 in/out) ----
// 4-deep gather pipeline (R10-proven): meta for batch i+1 prefetched before
// batch i's gathers are consumed -> 4 independent gathers in flight per wave.

__global__ __launch_bounds__(256) void agg_k(const __half2* __restrict__ Th, __half2* __restrict__ Hh,
                                             const int2* __restrict__ meta,
                                             const int* __restrict__ row_ptr, const int* __restrict__ cnt,
                                             const float* __restrict__ dinv, const float* __restrict__ bias,
                                             int n) {
    int wave = threadIdx.x >> 6, lane = threadIdx.x & 63;
    int d = blockIdx.x * 4 + wave;
    if (d >= n) return;
    float nd = dinv[d];
    float2 ts = __half22float2(Th[(size_t)d * 64 + lane]);
    float ax = nd * ts.x;
    float ay = nd * ts.y;
    int start = row_ptr[d];
    int c = cnt[d];
    int j = 0;
    if (c >= 8) {
        int2 m0 = meta[start + 0];
        int2 m1 = meta[start + 1];
        int2 m2 = meta[start + 2];
        int2 m3 = meta[start + 3];
        for (; j + 8 <= c; j += 4) {
            int2 n0 = meta[start + j + 4];
            int2 n1 = meta[start + j + 5];
            int2 n2 = meta[start + j + 6];
            int2 n3 = meta[start + j + 7];
            float2 t0 = __half22float2(Th[(size_t)m0.x * 64 + lane]);
            float2 t1 = __half22float2(Th[(size_t)m1.x * 64 + lane]);
            float2 t2 = __half22float2(Th[(size_t)m2.x * 64 + lane]);
            float2 t3 = __half22float2(Th[(size_t)m3.x * 64 + lane]);
            float w0 = __int_as_float(m0.y);
            float w1 = __int_as_float(m1.y);
            float w2 = __int_as_float(m2.y);
            float w3 = __int_as_float(m3.y);
            ax = fmaf(w0, t0.x, ax); ay = fmaf(w0, t0.y, ay);
            ax = fmaf(w1, t1.x, ax); ay = fmaf(w1, t1.y, ay);
            ax = fmaf(w2, t2.x, ax); ay = fmaf(w2, t2.y, ay);
            ax = fmaf(w3, t3.x, ax); ay = fmaf(w3, t3.y, ay);
            m0 = n0; m1 = n1; m2 = n2; m3 = n3;
        }
        // drain the preloaded batch
        {
            float2 t0 = __half22float2(Th[(size_t)m0.x * 64 + lane]);
            float2 t1 = __half22float2(Th[(size_t)m1.x * 64 + lane]);
            float2 t2 = __half22float2(Th[(size_t)m2.x * 64 + lane]);
            float2 t3 = __half22float2(Th[(size_t)m3.x * 64 + lane]);
            float w0 = __int_as_float(m0.y);
            float w1 = __int_as_float(m1.y);
            float w2 = __int_as_float(m2.y);
            float w3 = __int_as_float(m3.y);
            ax = fmaf(w0, t0.x, ax); ay = fmaf(w0, t0.y, ay);
            ax = fmaf(w1, t1.x, ax); ay = fmaf(w1, t1.y, ay);
            ax = fmaf(w2, t2.x, ax); ay = fmaf(w2, t2.y, ay);
            ax = fmaf(w3, t3.x, ax); ay = fmaf(w3, t3.y, ay);
            j += 4;
        }
    }
    for (; j < c; j++) {
        int2 m0 = meta[start + j];
        float2 t0 = __half22float2(Th[(size_t)m0.x * 64 + lane]);
        float w0 = __int_as_float(m0.y);
        ax = fmaf(w0, t0.x, ax);
        ay = fmaf(w0, t0.y, ay);
    }
    float2 bb = *(const float2*)(bias + 2 * lane);
    float vx = fmaf(nd, ax, bb.x);
    float vy = fmaf(nd, ay, bb.y);
    vx = vx > 0.f ? vx : 0.f;
    vy = vy > 0.f ? vy : 0.f;
    Hh[(size_t)d * 64 + lane] = __floats2half2_rn(vx, vy);
}

// ---------------- final FC(128->10) + softmax: MFMA 64x16 per block --------

__global__ __launch_bounds__(256) void fc_k(const _Float16* __restrict__ Hh,
                                            const _Float16* __restrict__ fwh,
                                            const float* __restrict__ FB,
                                            float* __restrict__ out, int n) {
    __shared__ __align__(16) _Float16 Hs[64][136];   // 64 rows x 128, +8 pad
    __shared__ __align__(16) _Float16 Bs[16][136];   // fwh staged
    __shared__ float fbs[16];
    int tid = threadIdx.x;
    int r0 = blockIdx.x * 64;
    #pragma unroll
    for (int j = 0; j < 4; j++) {
        int idx = tid + j * 256;
        int r = idx >> 4;                 // 16 chunks per row
        int c8 = (idx & 15) * 8;
        int gm = r0 + r;
        half8 v = {0, 0, 0, 0, 0, 0, 0, 0};
        if (gm < n) v = *(const half8*)(Hh + (size_t)gm * 128 + c8);
        *(half8*)(&Hs[r][c8]) = v;
    }
    {
        int r = tid >> 4;
        int c8 = (tid & 15) * 8;
        *(half8*)(&Bs[r][c8]) = *(const half8*)(fwh + r * 128 + c8);
    }
    if (tid < 16) fbs[tid] = (tid < 10) ? FB[tid] : 0.f;
    __syncthreads();

    int w = tid >> 6, l = tid & 63;
    int lr = l & 15, lk = l >> 4;
    half8 af[4], bf[4];
    #pragma unroll
    for (int ks = 0; ks < 4; ks++) {
        af[ks] = *(const half8*)(&Hs[w * 16 + lr][ks * 32 + lk * 8]);
        bf[ks] = *(const half8*)(&Bs[lr][ks * 32 + lk * 8]);
    }
    float4v acc = (float4v){0.f, 0.f, 0.f, 0.f};
    #pragma unroll
    for (int ks = 0; ks < 4; ks++)
        acc = __builtin_amdgcn_mfma_f32_16x16x32_f16(af[ks], bf[ks], acc, 0, 0, 0);

    float fbv = fbs[lr];
    float v[4], mx[4], e[4], sm[4];
    #pragma unroll
    for (int j = 0; j < 4; j++) v[j] = (lr < 10) ? acc[j] + fbv : -1e30f;
    #pragma unroll
    for (int j = 0; j < 4; j++) mx[j] = v[j];
    #pragma unroll
    for (int off = 1; off < 16; off <<= 1) {
        #pragma unroll
        for (int j = 0; j < 4; j++) mx[j] = fmaxf(mx[j], __shfl_xor(mx[j], off));
    }
    #pragma unroll
    for (int j = 0; j < 4; j++) e[j] = __expf(v[j] - mx[j]);
    #pragma unroll
    for (int j = 0; j < 4; j++) sm[j] = e[j];
    #pragma unroll
    for (int off = 1; off < 16; off <<= 1) {
        #pragma unroll
        for (int j = 0; j < 4; j++) sm[j] += __shfl_xor(sm[j], off);
    }
    if (lr < 10) {
        #pragma unroll
        for (int j = 0; j < 4; j++) {
            int gm = r0 + w * 16 + lk * 4 + j;
            if (gm < n) out[(size_t)gm * 10 + lr] = e[j] / sm[j];
        }
    }
}

// ---------------- host ----------------

extern "C" void kernel_launch(void* const* d_in, const int* in_sizes, int n_in,
                              void* d_out, int out_size, void* d_ws, size_t ws_size,
                              hipStream_t stream) {
    const float* x  = (const float*)d_in[0];
    const int*   ei = (const int*)d_in[1];
    const float* ew = (const float*)d_in[2];
    const float* W1 = (const float*)d_in[3];
    const float* b1 = (const float*)d_in[4];
    const float* W2 = (const float*)d_in[5];
    const float* b2 = (const float*)d_in[6];
    const float* W3 = (const float*)d_in[7];
    const float* b3 = (const float*)d_in[8];
    const float* FW = (const float*)d_in[9];
    const float* FB = (const float*)d_in[10];
    float* out = (float*)d_out;

    int Hd = in_sizes[4];            // 128
    int F  = in_sizes[3] / Hd;       // 256
    int N  = in_sizes[0] / F;        // 50000
    int E  = in_sizes[1] / 2;        // 800000

    const int* src = ei;
    const int* dst = ei + E;

    char* ws = (char*)d_ws;
    size_t off = 0;
    auto alloc = [&](size_t bytes) -> void* {
        void* p = ws + off;
        off = (off + bytes + 255) & ~(size_t)255;
        return p;
    };
    float*    dinv    = (float*)alloc((size_t)N * 4);
    int*      cnt     = (int*)alloc((size_t)N * 4);
    int*      row_ptr = (int*)alloc((size_t)N * 4);
    int*      rank    = (int*)alloc((size_t)E * 4);
    int*      bsum    = (int*)alloc(4096);
    int2*     meta    = (int2*)alloc((size_t)E * 8);
    _Float16* T       = (_Float16*)alloc((size_t)N * Hd * 2);
    _Float16* Hh      = (_Float16*)alloc((size_t)N * Hd * 2);
    _Float16* WT1     = (_Float16*)alloc(((size_t)(F + 2 * Hd) * Hd + 16 * 128) * 2);
    _Float16* WT2     = WT1 + (size_t)F * Hd;
    _Float16* WT3     = WT2 + (size_t)Hd * Hd;
    _Float16* fwh     = WT3 + (size_t)Hd * Hd;

    int nb = (N + 1023) / 1024;

    // weight converts
    int nw = (F + 2 * Hd) * Hd + 16 * 128;
    cvtw_k<<<(nw + 255) / 256, 256, 0, stream>>>(W1, W2, W3, FW, WT1, WT2, WT3, fwh, F, Hd);

    // CSR build
    hipMemsetAsync(cnt, 0, (size_t)N * 4, stream);
    rank_k<<<(E + 255) / 256, 256, 0, stream>>>(dst, cnt, rank, E);
    scan1_k<<<nb, 256, 0, stream>>>(cnt, bsum, N);
    scan2_k<<<1, 64, 0, stream>>>(bsum, nb);
    scan3_k<<<nb, 256, 0, stream>>>(cnt, bsum, row_ptr, N);
    fill_k<<<(E + 255) / 256, 256, 0, stream>>>(src, dst, ew, row_ptr, rank, meta, E);
    deg_k<<<(N + 255) / 256, 256, 0, stream>>>(meta, row_ptr, cnt, dinv, N);
    scale_k<<<(E + 255) / 256, 256, 0, stream>>>(meta, dinv, E);

    int gb = (N + 63) / 64;
    int ab = (N + 3) / 4;
    // layer 1 (fused fp32->fp16 convert in A staging)
    gemmx_k<<<gb, 256, 0, stream>>>(x, WT1, T, N, F);
    agg_k<<<ab, 256, 0, stream>>>((const __half2*)T, (__half2*)Hh, meta, row_ptr, cnt, dinv, b1, N);
    // layer 2
    gemmh_k<<<gb, 256, 0, stream>>>(Hh, WT2, T, N, Hd);
    agg_k<<<ab, 256, 0, stream>>>((const __half2*)T, (__half2*)Hh, meta, row_ptr, cnt, dinv, b2, N);
    // layer 3
    gemmh_k<<<gb, 256, 0, stream>>>(Hh, WT3, T, N, Hd);
    agg_k<<<ab, 256, 0, stream>>>((const __half2*)T, (__half2*)Hh, meta, row_ptr, cnt, dinv, b3, N);
    // FC + softmax (MFMA)
    fc_k<<<gb, 256, 0, stream>>>(Hh, fwh, FB, out, N);
}